// Round 6
// baseline (240.299 us; speedup 1.0000x reference)
//
#include <hip/hip_runtime.h>

typedef float v2f __attribute__((ext_vector_type(2)));

namespace {
constexpr int T_LEN = 8192;   // T
constexpr int C_CH  = 512;    // C
constexpr int B_SZ  = 8;      // B
constexpr int RPT   = 16;     // outputs per thread (contiguous)
constexpr int NTH   = 256;    // threads per block
constexpr int TILE  = RPT * NTH;      // 4096 outputs per block
constexpr int TPR   = T_LEN / TILE;   // tiles per row = 2
constexpr int NZP   = RPT + 6;        // z-pairs per thread: si = 0..21
}

// Fused: upsample-by-2 (12-tap polyphase) -> snake-beta -> downsample-by-2 (12-tap).
//   y[2s]   = 2*sum_a uf[11-2a] * x[clamp(s-3+a)]   (a=0..5)
//   y[2s+1] = 2*sum_a uf[10-2a] * x[clamp(s-2+a)]
//   z[m]    = y[m] + (1 - cos(2*y[m]*e^alpha)) / (2*(e^beta+1e-9))   (half-angle)
//   out[n]  = sum_j df[j] * z[clamp(2n-5+j, 0, 2T-1)]
//           = sum_{k=0..6} w[k] (.) zp[nn+k]   (packed; w[0]={0,df0},
//             w[k]={df[2k-1],df[2k]}, w[6]={df11,0})
// Register sliding-window: thread owns outputs N..N+15; x-window x[N-8..N+23]
// (8 aligned float4 loads), z-pairs zp[0..21] for s = N-3..N+18, all in regs.
// No LDS, no barriers.
__global__ __launch_bounds__(NTH)
void aaa_fused(const float* __restrict__ x,
               const float* __restrict__ alpha,
               const float* __restrict__ beta,
               const float* __restrict__ upf,
               const float* __restrict__ dnf,
               float* __restrict__ out)
{
    const int tid  = threadIdx.x;
    const int bid  = blockIdx.x;
    const int tile = bid & (TPR - 1);
    const int row  = bid >> 1;           // b*C + c   (TPR == 2)
    const int ch   = row & (C_CH - 1);
    const int Nl   = tile * TILE + tid * RPT;   // local output base in row

    const float* __restrict__ xr = x + (size_t)row * T_LEN;
    float* __restrict__ outr     = out + (size_t)row * T_LEN;

    // per-channel snake constants (broadcast loads)
    const float av  = expf(alpha[ch]);
    const float rb  = 1.0f / (expf(beta[ch]) + 1e-9f);
    const float avp = av * 0.3183098861837907f;  // a/pi: cos(2*a*y) = cos2pi(y*avp)
    const float hrb = 0.5f * rb;

    // filter taps into registers (broadcast, L1-hit)
    float cE[6], cO[6];
#pragma unroll
    for (int i = 0; i < 6; ++i) {
        cE[i] = 2.0f * upf[11 - 2 * i];
        cO[i] = 2.0f * upf[10 - 2 * i];
    }
    v2f w[7];
    w[0] = v2f{0.0f, dnf[0]};
#pragma unroll
    for (int k = 1; k < 6; ++k) w[k] = v2f{dnf[2 * k - 1], dnf[2 * k]};
    w[6] = v2f{dnf[11], 0.0f};

    // ---- x window: xw[i] = x[clamp(Nl-8+i)] , i = 0..31 ----
    float xw[32];
    if (Nl != 0 && Nl != T_LEN - RPT) {
        // interior thread: Nl in [16, 8160] -> [Nl-8, Nl+23] inside row, aligned
        const float4* __restrict__ p4 = reinterpret_cast<const float4*>(xr + Nl - 8);
#pragma unroll
        for (int q = 0; q < 8; ++q) {
            const float4 v = p4[q];
            xw[4 * q + 0] = v.x; xw[4 * q + 1] = v.y;
            xw[4 * q + 2] = v.z; xw[4 * q + 3] = v.w;
        }
    } else {
        // row-edge thread: clamped scalar loads (edge replicate == reference pad)
#pragma unroll
        for (int i = 0; i < 32; ++i) {
            int g = Nl - 8 + i;
            g = min(max(g, 0), T_LEN - 1);
            xw[i] = xr[g];
        }
    }

    // ---- z-pairs: zp[si] = {z[2s], z[2s+1]}, s = Nl-3+si, si = 0..21 ----
    // x[s-3+a] = xw[si+2+a]
    v2f zp[NZP];
#pragma unroll
    for (int si = 0; si < NZP; ++si) {
        const float x0 = xw[si + 2];
        const float x1 = xw[si + 3];
        const float x2 = xw[si + 4];
        const float x3 = xw[si + 5];
        const float x4 = xw[si + 6];
        const float x5 = xw[si + 7];
        const float x6 = xw[si + 8];
        const float ye = cE[0]*x0 + cE[1]*x1 + cE[2]*x2 + cE[3]*x3 + cE[4]*x4 + cE[5]*x5;
        const float yo = cO[0]*x1 + cO[1]*x2 + cO[2]*x3 + cO[3]*x4 + cO[4]*x5 + cO[5]*x6;
        float ue = ye * avp;  ue -= floorf(ue);        // revolutions, range-reduced
        float uo = yo * avp;  uo -= floorf(uo);
        const float ce = __builtin_amdgcn_cosf(ue);    // v_cos_f32
        const float co = __builtin_amdgcn_cosf(uo);
        zp[si] = v2f{(ye + hrb) - hrb * ce, (yo + hrb) - hrb * co};
    }

    // ---- 12-tap downsample, packed: out[Nl+nn] = sum_k w[k] . zp[nn+k] ----
    float o[RPT];
#pragma unroll
    for (int nn = 0; nn < RPT; ++nn) {
        v2f acc = w[0] * zp[nn];
#pragma unroll
        for (int k = 1; k < 7; ++k) acc += w[k] * zp[nn + k];   // v_pk_fma_f32
        o[nn] = acc.x + acc.y;
    }

    // ---- row-boundary overrides (static clamped-tap formulas) ----
    // df components: df0=w0.y df1=w1.x df2=w1.y df3=w2.x df4=w2.y df5=w3.x
    //                df6=w3.y df7=w4.x df8=w4.y df9=w5.x df10=w5.y df11=w6.x
    if (Nl == 0) {
        // zp[si] <-> s = si-3 ; z[0] = zp[3].x
        const float d0=w[0].y, d1=w[1].x, d2=w[1].y, d3=w[2].x, d4=w[2].y, d5=w[3].x,
                    d6=w[3].y, d7=w[4].x, d8=w[4].y, d9=w[5].x, d10=w[5].y, d11=w[6].x;
        o[0] = (d0+d1+d2+d3+d4+d5)*zp[3].x + d6*zp[3].y + d7*zp[4].x + d8*zp[4].y
             + d9*zp[5].x + d10*zp[5].y + d11*zp[6].x;
        o[1] = (d0+d1+d2+d3)*zp[3].x + d4*zp[3].y + d5*zp[4].x + d6*zp[4].y
             + d7*zp[5].x + d8*zp[5].y + d9*zp[6].x + d10*zp[6].y + d11*zp[7].x;
        o[2] = (d0+d1)*zp[3].x + d2*zp[3].y + d3*zp[4].x + d4*zp[4].y + d5*zp[5].x
             + d6*zp[5].y + d7*zp[6].x + d8*zp[6].y + d9*zp[7].x + d10*zp[7].y
             + d11*zp[8].x;
    }
    if (Nl == T_LEN - RPT) {
        // zp[si] <-> s = 8173+si ; z[2T-1] = zp[18].y ; zp[19..21] from clamped x,
        // overridden below per the reference's z-index clamp semantics.
        const float d7=w[4].x, d8=w[4].y, d9=w[5].x, d10=w[5].y, d11=w[6].x;
        {   // n = T-3 (o[13]): valid pairs zp[13..18], then clamped tap d11
            v2f acc = w[0] * zp[13];
#pragma unroll
            for (int k = 1; k < 6; ++k) acc += w[k] * zp[13 + k];
            o[13] = acc.x + acc.y + d11 * zp[18].y;
        }
        {   // n = T-2 (o[14]): valid pairs zp[14..18], clamped taps d9+d10+d11
            v2f acc = w[0] * zp[14];
#pragma unroll
            for (int k = 1; k < 5; ++k) acc += w[k] * zp[14 + k];
            o[14] = acc.x + acc.y + (d9 + d10 + d11) * zp[18].y;
        }
        {   // n = T-1 (o[15]): valid pairs zp[15..18], clamped taps d7..d11
            v2f acc = w[0] * zp[15];
#pragma unroll
            for (int k = 1; k < 4; ++k) acc += w[k] * zp[15 + k];
            o[15] = acc.x + acc.y + (d7 + d8 + d9 + d10 + d11) * zp[18].y;
        }
    }

    // ---- 4 aligned float4 stores ----
    float4* __restrict__ po = reinterpret_cast<float4*>(outr + Nl);
#pragma unroll
    for (int q = 0; q < 4; ++q)
        po[q] = float4{o[4*q + 0], o[4*q + 1], o[4*q + 2], o[4*q + 3]};
}

extern "C" void kernel_launch(void* const* d_in, const int* in_sizes, int n_in,
                              void* d_out, int out_size, void* d_ws, size_t ws_size,
                              hipStream_t stream)
{
    (void)in_sizes; (void)n_in; (void)out_size; (void)d_ws; (void)ws_size;
    const float* x     = (const float*)d_in[0];
    const float* alpha = (const float*)d_in[1];
    const float* beta  = (const float*)d_in[2];
    const float* upf   = (const float*)d_in[3];
    const float* dnf   = (const float*)d_in[4];
    float* out = (float*)d_out;

    dim3 grid(B_SZ * C_CH * TPR);   // 8192 blocks
    dim3 block(NTH);
    aaa_fused<<<grid, block, 0, stream>>>(x, alpha, beta, upf, dnf, out);
}